// Round 21
// baseline (86.519 us; speedup 1.0000x reference)
//
#include <hip/hip_runtime.h>
#include <hip/hip_bf16.h>

using bf16x8 = __attribute__((ext_vector_type(8))) __bf16;
using f32x4  = __attribute__((ext_vector_type(4))) float;

#define MTOT   16384
#define DMODEL 1024
#define DSTATE 64
#define KBIG   1088

__device__ __forceinline__ ushort f2b(float f) {
  __hip_bfloat16 h = __float2bfloat16(f);
  return *reinterpret_cast<ushort*>(&h);
}

// async global->LDS, 16 bytes per lane. LDS dest = wave-uniform base + lane*16.
__device__ __forceinline__ void gld_lds16(const ushort* g, const char* l) {
  using gptr_t = const __attribute__((address_space(1))) uint32_t*;
  using lptr_t = __attribute__((address_space(3))) uint32_t*;
  __builtin_amdgcn_global_load_lds(
      reinterpret_cast<gptr_t>(reinterpret_cast<uintptr_t>(g)),
      reinterpret_cast<lptr_t>(static_cast<uint32_t>(reinterpret_cast<uintptr_t>(l))),
      16, 0, 0);
}

#define BARRIER() do { asm volatile("" ::: "memory"); __builtin_amdgcn_s_barrier(); asm volatile("" ::: "memory"); } while (0)
#define VMCNT6() asm volatile("s_waitcnt vmcnt(6)" ::: "memory")
#define VMCNT0() asm volatile("s_waitcnt vmcnt(0)" ::: "memory")

// ---------------- prep: coalesced tile-transpose for Wt, Btu; aSig (R12-proven) --------
__global__ __launch_bounds__(256) void prep_wb(const float* __restrict__ A_diag,
    const float* __restrict__ B, const float* __restrict__ C, const float* __restrict__ D,
    ushort* __restrict__ Wt, ushort* __restrict__ Btu, float* __restrict__ aSig) {
  __shared__ float tile[64][65];
  int bid = blockIdx.x;
  int tid = threadIdx.x;
  int r = tid >> 2;
  if (bid < 272) {
    int bk = bid % 17, bn = bid / 17;
    int k0 = bk * 64, n0 = bn * 64;
    const float* srow = (k0 + r < DSTATE)
        ? (C + (size_t)(k0 + r) * DMODEL + n0)
        : (D + (size_t)(k0 + r - DSTATE) * DMODEL + n0);
#pragma unroll
    for (int it = 0; it < 4; ++it) {
      int c4 = (tid & 3) + it * 4;
      float4 v = *reinterpret_cast<const float4*>(srow + c4 * 4);
      tile[r][c4 * 4 + 0] = v.x; tile[r][c4 * 4 + 1] = v.y;
      tile[r][c4 * 4 + 2] = v.z; tile[r][c4 * 4 + 3] = v.w;
    }
    __syncthreads();
#pragma unroll
    for (int it = 0; it < 2; ++it) {
      int gq = (tid & 3) + it * 4;  // 8-k group 0..7
      ushort o[8];
#pragma unroll
      for (int j = 0; j < 8; ++j) o[j] = f2b(tile[gq * 8 + j][r]);
      *reinterpret_cast<uint4*>(&Wt[(size_t)(n0 + r) * KBIG + k0 + gq * 8]) =
          *reinterpret_cast<uint4*>(o);
    }
  } else {
    int k0 = (bid - 272) * 64;
    const float* srow = B + (size_t)(k0 + r) * DSTATE;
#pragma unroll
    for (int it = 0; it < 4; ++it) {
      int c4 = (tid & 3) + it * 4;
      float4 v = *reinterpret_cast<const float4*>(srow + c4 * 4);
      tile[r][c4 * 4 + 0] = v.x; tile[r][c4 * 4 + 1] = v.y;
      tile[r][c4 * 4 + 2] = v.z; tile[r][c4 * 4 + 3] = v.w;
    }
    __syncthreads();
#pragma unroll
    for (int it = 0; it < 2; ++it) {
      int gq = (tid & 3) + it * 4;
      ushort o[8];
#pragma unroll
      for (int j = 0; j < 8; ++j) o[j] = f2b(tile[gq * 8 + j][r]);
      *reinterpret_cast<uint4*>(&Btu[(size_t)r * DMODEL + k0 + gq * 8]) =
          *reinterpret_cast<uint4*>(o);
    }
    if (bid == 272 && tid < DSTATE) aSig[tid] = 1.0f / (1.0f + expf(-A_diag[tid]));
  }
}

// ---------------- fused v3 (R18-proven, deep TLP): x -> Z, u = x@B, chunk scan ---------
__global__ __launch_bounds__(256) void fused_xu(const float* __restrict__ x,
    const ushort* __restrict__ Btu, const float* __restrict__ aSig,
    ushort* __restrict__ Z, float* __restrict__ Uloc, float* __restrict__ carry) {
  __shared__ ushort As[16][136];
  __shared__ float  Ul[16][68];
  int tid = threadIdx.x;
  int w = tid >> 6, lane = tid & 63;
  int l16 = lane & 15, lh = lane >> 4;
  int row0 = blockIdx.x * 16;
  int r = tid >> 4, kq = tid & 15;

  f32x4 acc = {};
  const float* srcBase = x + (size_t)(row0 + r) * 1024 + kq * 8;
  float4 xv0 = *reinterpret_cast<const float4*>(srcBase);
  float4 xv1 = *reinterpret_cast<const float4*>(srcBase + 4);
  for (int c = 0; c < 8; ++c) {
    int k0 = c * 128;
    ushort o[8] = {f2b(xv0.x), f2b(xv0.y), f2b(xv0.z), f2b(xv0.w),
                   f2b(xv1.x), f2b(xv1.y), f2b(xv1.z), f2b(xv1.w)};
    uint4 pk = *reinterpret_cast<uint4*>(o);
    *reinterpret_cast<uint4*>(&Z[(size_t)(row0 + r) * KBIG + DSTATE + k0 + kq * 8]) = pk;
    *reinterpret_cast<uint4*>(&As[r][kq * 8]) = pk;
    __syncthreads();
    if (c < 7) {
      const float* src = srcBase + k0 + 128;
      xv0 = *reinterpret_cast<const float4*>(src);
      xv1 = *reinterpret_cast<const float4*>(src + 4);
    }
#pragma unroll
    for (int ks = 0; ks < 4; ++ks) {
      bf16x8 af = *reinterpret_cast<const bf16x8*>(&As[l16][ks * 32 + lh * 8]);
      bf16x8 bf = *reinterpret_cast<const bf16x8*>(
          &Btu[(size_t)(w * 16 + l16) * 1024 + k0 + ks * 32 + lh * 8]);
      acc = __builtin_amdgcn_mfma_f32_16x16x32_bf16(af, bf, acc, 0, 0, 0);
    }
    __syncthreads();
  }
#pragma unroll
  for (int j = 0; j < 4; ++j)
    Ul[lh * 4 + j][w * 16 + l16] = acc[j];
  __syncthreads();
  if (w == 0) {
    int g = blockIdx.x;
    float as = aSig[lane];
    float h = 0.0f;
#pragma unroll
    for (int i = 0; i < 16; ++i) {
      h = fmaf(as, h, Ul[i][lane]);
      Uloc[(size_t)(g * 16 + i) * 64 + lane] = h;
    }
    carry[(size_t)g * 64 + lane] = h;
  }
}

// ---------------- scan fix v2 (R18-proven): batched prefix + apply + write Z ------
__global__ __launch_bounds__(128) void scan_fix2(const float* __restrict__ aSig,
    const float* __restrict__ Uloc, const float* __restrict__ carry,
    ushort* __restrict__ Z) {
  int w = threadIdx.x >> 6, s = threadIdx.x & 63;
  int g = blockIdx.x * 2 + w;          // 0..1023
  int b = g >> 8, c = g & 255;
  float as = aSig[s];
  float aL = as;
#pragma unroll
  for (int q = 0; q < 4; ++q) aL *= aL;  // as^16
  const float* cb = carry + ((size_t)b << 8) * 64 + s;
  float H = 0.0f;
  for (int c0 = 0; c0 < 256; c0 += 16) {
    if (c0 >= c) break;                  // wave-uniform
    float v[16];
#pragma unroll
    for (int i = 0; i < 16; ++i) v[i] = cb[(size_t)(c0 + i) * 64];
#pragma unroll
    for (int i = 0; i < 16; ++i)
      if (c0 + i < c) H = fmaf(aL, H, v[i]);   // wave-uniform predicate
  }
  float p = as;
  size_t ubase = (size_t)g * 16 * 64 + s;
  size_t zbase = (size_t)(g * 16) * KBIG + s;
#pragma unroll
  for (int i = 0; i < 16; ++i) {
    float h = fmaf(p, H, Uloc[ubase + (size_t)i * 64]);
    p *= as;
    Z[zbase + (size_t)i * KBIG] = f2b(h);
  }
}

// ---------------- 256x256 8-phase GEMM, faithful m201-template port ----------------
// 8 waves (2M x 4N), per-wave 128x64, BK=64, 2 K-tiles / 8 phases per iteration.
// Per phase: {ds_read quadrant subtile (12/4/8/0 b128) ; stage 1 HALF-TILE (2 gld) ;
// BARRIER ; setprio ; 16 MFMA ; setprio ; [vmcnt(6) at ph4/ph8] ; BARRIER}.
// Stage order (region-free derived): ph1:A-h1(t+1) | ph2..5: B-h0,B-h1,A-h0,A-h1(t+2)
// | ph6..8: B-h0,B-h1,A-h0(t+3). vmcnt(6) = 3 half-tiles in flight; never 0 mid-loop.
// Prologue: t0 full + t1 3 halves, vmcnt(6). Even tiles buf0, odd buf1. NT=17 tail.
// Max live frags 16 (64 VGPR) + acc 128 AGPR: R5-proven no-spill footprint.
__global__ __launch_bounds__(512) void gemm256(const ushort* __restrict__ A, int lda,
                                               const ushort* __restrict__ Bt, int ldb,
                                               float* __restrict__ Cc, int ldc, int K) {
  extern __shared__ __align__(128) char smem[];   // 2 bufs x (A 32K + B 32K) = 128 KB
  const int tid = threadIdx.x;
  const int wid = tid >> 6, lane = tid & 63;
  const int wm = wid >> 2, wn = wid & 3;
  const int l16 = lane & 15, lh = lane >> 4;

  int bid = blockIdx.x;
  int swz = (bid & 7) * ((int)gridDim.x >> 3) + (bid >> 3);  // 256 % 8 == 0
  const int bmRow = (swz >> 2) * 256;
  const int bnCol = (swz & 3) * 256;
  const int NT = K / 64;   // 17 (odd)

  const int cswz = ((lh ^ (l16 & 7)) << 4);
  const int sRow = lane >> 3;
  const int sCol = (((lane & 7) ^ (lane >> 3)) << 3);

  const ushort* aBase = A + (size_t)(bmRow + wid * 8 + sRow) * lda + sCol;
  const ushort* bBase = Bt + (size_t)(bnCol + wid * 8 + sRow) * ldb + sCol;

  f32x4 acc[8][4] = {};
  bf16x8 a0[8], a1[8], b0[4], b1[4];

  // stage one HALF (128 rows = 2 block-wide 1KB-per-wave calls) of A or B, tile t
  auto stageAH = [&](int buf, int t, int h) {
    const ushort* g = aBase + (size_t)(h * 128) * lda + (size_t)t * 64;
    const char* d = smem + buf * 65536 + (h * 128 + wid * 8) * 128;
    gld_lds16(g, d);
    gld_lds16(g + (size_t)64 * lda, d + 64 * 128);
  };
  auto stageBH = [&](int buf, int t, int h) {
    const ushort* g = bBase + (size_t)(h * 128) * ldb + (size_t)t * 64;
    const char* d = smem + buf * 65536 + 32768 + (h * 128 + wid * 8) * 128;
    gld_lds16(g, d);
    gld_lds16(g + (size_t)64 * ldb, d + 64 * 128);
  };
  auto readA = [&](bf16x8 (&dst)[8], int buf, int qm) {
#pragma unroll
    for (int m = 0; m < 4; ++m)
#pragma unroll
      for (int ks = 0; ks < 2; ++ks)
        dst[m * 2 + ks] = *reinterpret_cast<const bf16x8*>(
            smem + buf * 65536 + (wm * 128 + qm * 64 + m * 16 + l16) * 128 + (cswz ^ (ks * 64)));
  };
  auto readB = [&](bf16x8 (&dst)[4], int buf, int qn) {
#pragma unroll
    for (int n = 0; n < 2; ++n)
#pragma unroll
      for (int ks = 0; ks < 2; ++ks)
        dst[n * 2 + ks] = *reinterpret_cast<const bf16x8*>(
            smem + buf * 65536 + 32768 + (wn * 64 + qn * 32 + n * 16 + l16) * 128 + (cswz ^ (ks * 64)));
  };
  auto mfmaQ = [&](bf16x8 (&a8)[8], bf16x8 (&b4)[4], int qm, int qn) {
    __builtin_amdgcn_s_setprio(1);
#pragma unroll
    for (int ks = 0; ks < 2; ++ks)
#pragma unroll
      for (int m = 0; m < 4; ++m)
#pragma unroll
        for (int n = 0; n < 2; ++n)
          acc[qm * 4 + m][qn * 2 + n] = __builtin_amdgcn_mfma_f32_16x16x32_bf16(
              a8[m * 2 + ks], b4[n * 2 + ks], acc[qm * 4 + m][qn * 2 + n], 0, 0, 0);
    __builtin_amdgcn_s_setprio(0);
  };

  // prologue: tile0 full (4 halves) + tile1 3 halves; keep tile1's 3 in flight
  stageBH(0, 0, 0); stageBH(0, 0, 1); stageAH(0, 0, 0); stageAH(0, 0, 1);
  stageBH(1, 1, 0); stageBH(1, 1, 1); stageAH(1, 1, 0);
  VMCNT6();
  BARRIER();

  for (int t = 0; t + 2 < NT; t += 2) {       // t = 0,2,...,14; tiles t (buf0), t+1 (buf1)
    const bool s3 = (t + 3 < NT);
    // ---- tile t @ buf0 ----
    // ph1
    readA(a0, 0, 0); readB(b0, 0, 0);
    stageAH(1, t + 1, 1);                     // last half of t+1
    BARRIER();
    mfmaQ(a0, b0, 0, 0);
    BARRIER();
    // ph2
    readB(b1, 0, 1);
    stageBH(0, t + 2, 0);
    BARRIER();
    mfmaQ(a0, b1, 0, 1);
    BARRIER();
    // ph3
    readA(a1, 0, 1);
    stageBH(0, t + 2, 1);
    BARRIER();
    mfmaQ(a1, b0, 1, 0);
    BARRIER();
    // ph4
    stageAH(0, t + 2, 0);
    BARRIER();
    mfmaQ(a1, b1, 1, 1);
    VMCNT6();                                  // drains t+1's halves; keeps ph2-4's 3
    BARRIER();
    // ---- tile t+1 @ buf1 ----
    // ph5
    readA(a0, 1, 0); readB(b0, 1, 0);
    stageAH(0, t + 2, 1);
    BARRIER();
    mfmaQ(a0, b0, 0, 0);
    BARRIER();
    // ph6
    readB(b1, 1, 1);
    if (s3) stageBH(1, t + 3, 0);
    BARRIER();
    mfmaQ(a0, b1, 0, 1);
    BARRIER();
    // ph7
    readA(a1, 1, 1);
    if (s3) stageBH(1, t + 3, 1);
    BARRIER();
    mfmaQ(a1, b0, 1, 0);
    BARRIER();
    // ph8
    if (s3) stageAH(1, t + 3, 0);
    BARRIER();
    mfmaQ(a1, b1, 1, 1);
    if (s3) { VMCNT6(); } else { VMCNT0(); }   // drains t+2 (next ph1's buf0)
    BARRIER();
  }

  // tail: tile 16 @ buf0 (fully drained by final VMCNT0)
  readA(a0, 0, 0); readB(b0, 0, 0);
  BARRIER();
  mfmaQ(a0, b0, 0, 0);
  BARRIER();
  readB(b1, 0, 1);
  BARRIER();
  mfmaQ(a0, b1, 0, 1);
  BARRIER();
  readA(a1, 0, 1);
  BARRIER();
  mfmaQ(a1, b0, 1, 0);
  BARRIER();
  mfmaQ(a1, b1, 1, 1);

  // epilogue: C/D 16x16 layout: col = l16, row = lh*4 + j
#pragma unroll
  for (int i = 0; i < 8; ++i)
#pragma unroll
    for (int jn = 0; jn < 4; ++jn)
#pragma unroll
      for (int j = 0; j < 4; ++j) {
        int r = bmRow + wm * 128 + (i >> 2) * 64 + (i & 3) * 16 + lh * 4 + j;
        int c = bnCol + wn * 64 + (jn >> 1) * 32 + (jn & 1) * 16 + l16;
        Cc[(size_t)r * ldc + c] = acc[i][jn][j];
      }
}

extern "C" void kernel_launch(void* const* d_in, const int* in_sizes, int n_in,
                              void* d_out, int out_size, void* d_ws, size_t ws_size,
                              hipStream_t stream) {
  const float* x      = (const float*)d_in[0];
  const float* A_diag = (const float*)d_in[1];
  const float* B      = (const float*)d_in[2];
  const float* C      = (const float*)d_in[3];
  const float* D      = (const float*)d_in[4];
  float* y = (float*)d_out;

  char* w = (char*)d_ws;
  ushort* Z     = (ushort*)(w);                 // [16384][1088] bf16  35,651,584
  ushort* Wt    = (ushort*)(w + 35651584);      // [1024][1088] bf16    2,228,224
  ushort* Btu   = (ushort*)(w + 37879808);      // [64][1024] bf16        131,072
  float*  Uloc  = (float*) (w + 38010880);      // [16384][64] f32      4,194,304
  float*  carry = (float*) (w + 42205184);      // [1024][64] f32         262,144
  float*  aSig  = (float*) (w + 42467328);      // [64] f32

  (void)hipFuncSetAttribute(reinterpret_cast<const void*>(&gemm256),
                            hipFuncAttributeMaxDynamicSharedMemorySize, 131072);

  prep_wb<<<dim3(288), dim3(256), 0, stream>>>(A_diag, B, C, D, Wt, Btu, aSig);
  fused_xu<<<dim3(1024), dim3(256), 0, stream>>>(x, Btu, aSig, Z, Uloc, carry);
  scan_fix2<<<dim3(512), dim3(128), 0, stream>>>(aSig, Uloc, carry, Z);
  // y = [h|x] @ [C;D] : M=16384, N=1024, K=1088  (256x256 tiles -> 256 blocks)
  gemm256<<<dim3(64 * 4), dim3(512), 131072, stream>>>(Z, KBIG, Wt, KBIG, y, DMODEL, KBIG);
}

// Round 22
// 82.706 us; speedup vs baseline: 1.0461x; 1.0461x over previous
//
#include <hip/hip_runtime.h>
#include <hip/hip_bf16.h>

using bf16x8 = __attribute__((ext_vector_type(8))) __bf16;
using f32x4  = __attribute__((ext_vector_type(4))) float;

#define MTOT   16384
#define DMODEL 1024
#define DSTATE 64
#define KBIG   1088

__device__ __forceinline__ ushort f2b(float f) {
  __hip_bfloat16 h = __float2bfloat16(f);
  return *reinterpret_cast<ushort*>(&h);
}

// async global->LDS, 16 bytes per lane. LDS dest = wave-uniform base + lane*16.
__device__ __forceinline__ void gld_lds16(const ushort* g, const char* l) {
  using gptr_t = const __attribute__((address_space(1))) uint32_t*;
  using lptr_t = __attribute__((address_space(3))) uint32_t*;
  __builtin_amdgcn_global_load_lds(
      reinterpret_cast<gptr_t>(reinterpret_cast<uintptr_t>(g)),
      reinterpret_cast<lptr_t>(static_cast<uint32_t>(reinterpret_cast<uintptr_t>(l))),
      16, 0, 0);
}

#define BARRIER() do { asm volatile("" ::: "memory"); __builtin_amdgcn_s_barrier(); asm volatile("" ::: "memory"); } while (0)
#define VMCNT8() asm volatile("s_waitcnt vmcnt(8)" ::: "memory")
#define VMCNT0() asm volatile("s_waitcnt vmcnt(0)" ::: "memory")

// ---------------- prep: coalesced tile-transpose for Wt, Btu; aSig (R12-proven) --------
__global__ __launch_bounds__(256) void prep_wb(const float* __restrict__ A_diag,
    const float* __restrict__ B, const float* __restrict__ C, const float* __restrict__ D,
    ushort* __restrict__ Wt, ushort* __restrict__ Btu, float* __restrict__ aSig) {
  __shared__ float tile[64][65];
  int bid = blockIdx.x;
  int tid = threadIdx.x;
  int r = tid >> 2;
  if (bid < 272) {
    int bk = bid % 17, bn = bid / 17;
    int k0 = bk * 64, n0 = bn * 64;
    const float* srow = (k0 + r < DSTATE)
        ? (C + (size_t)(k0 + r) * DMODEL + n0)
        : (D + (size_t)(k0 + r - DSTATE) * DMODEL + n0);
#pragma unroll
    for (int it = 0; it < 4; ++it) {
      int c4 = (tid & 3) + it * 4;
      float4 v = *reinterpret_cast<const float4*>(srow + c4 * 4);
      tile[r][c4 * 4 + 0] = v.x; tile[r][c4 * 4 + 1] = v.y;
      tile[r][c4 * 4 + 2] = v.z; tile[r][c4 * 4 + 3] = v.w;
    }
    __syncthreads();
#pragma unroll
    for (int it = 0; it < 2; ++it) {
      int gq = (tid & 3) + it * 4;  // 8-k group 0..7
      ushort o[8];
#pragma unroll
      for (int j = 0; j < 8; ++j) o[j] = f2b(tile[gq * 8 + j][r]);
      *reinterpret_cast<uint4*>(&Wt[(size_t)(n0 + r) * KBIG + k0 + gq * 8]) =
          *reinterpret_cast<uint4*>(o);
    }
  } else {
    int k0 = (bid - 272) * 64;
    const float* srow = B + (size_t)(k0 + r) * DSTATE;
#pragma unroll
    for (int it = 0; it < 4; ++it) {
      int c4 = (tid & 3) + it * 4;
      float4 v = *reinterpret_cast<const float4*>(srow + c4 * 4);
      tile[r][c4 * 4 + 0] = v.x; tile[r][c4 * 4 + 1] = v.y;
      tile[r][c4 * 4 + 2] = v.z; tile[r][c4 * 4 + 3] = v.w;
    }
    __syncthreads();
#pragma unroll
    for (int it = 0; it < 2; ++it) {
      int gq = (tid & 3) + it * 4;
      ushort o[8];
#pragma unroll
      for (int j = 0; j < 8; ++j) o[j] = f2b(tile[gq * 8 + j][r]);
      *reinterpret_cast<uint4*>(&Btu[(size_t)r * DMODEL + k0 + gq * 8]) =
          *reinterpret_cast<uint4*>(o);
    }
    if (bid == 272 && tid < DSTATE) aSig[tid] = 1.0f / (1.0f + expf(-A_diag[tid]));
  }
}

// ---------------- fused v3 (R18-proven, deep TLP): x -> Z, u = x@B, chunk scan ---------
__global__ __launch_bounds__(256) void fused_xu(const float* __restrict__ x,
    const ushort* __restrict__ Btu, const float* __restrict__ aSig,
    ushort* __restrict__ Z, float* __restrict__ Uloc, float* __restrict__ carry) {
  __shared__ ushort As[16][136];
  __shared__ float  Ul[16][68];
  int tid = threadIdx.x;
  int w = tid >> 6, lane = tid & 63;
  int l16 = lane & 15, lh = lane >> 4;
  int row0 = blockIdx.x * 16;
  int r = tid >> 4, kq = tid & 15;

  f32x4 acc = {};
  const float* srcBase = x + (size_t)(row0 + r) * 1024 + kq * 8;
  float4 xv0 = *reinterpret_cast<const float4*>(srcBase);
  float4 xv1 = *reinterpret_cast<const float4*>(srcBase + 4);
  for (int c = 0; c < 8; ++c) {
    int k0 = c * 128;
    ushort o[8] = {f2b(xv0.x), f2b(xv0.y), f2b(xv0.z), f2b(xv0.w),
                   f2b(xv1.x), f2b(xv1.y), f2b(xv1.z), f2b(xv1.w)};
    uint4 pk = *reinterpret_cast<uint4*>(o);
    *reinterpret_cast<uint4*>(&Z[(size_t)(row0 + r) * KBIG + DSTATE + k0 + kq * 8]) = pk;
    *reinterpret_cast<uint4*>(&As[r][kq * 8]) = pk;
    __syncthreads();
    if (c < 7) {
      const float* src = srcBase + k0 + 128;
      xv0 = *reinterpret_cast<const float4*>(src);
      xv1 = *reinterpret_cast<const float4*>(src + 4);
    }
#pragma unroll
    for (int ks = 0; ks < 4; ++ks) {
      bf16x8 af = *reinterpret_cast<const bf16x8*>(&As[l16][ks * 32 + lh * 8]);
      bf16x8 bf = *reinterpret_cast<const bf16x8*>(
          &Btu[(size_t)(w * 16 + l16) * 1024 + k0 + ks * 32 + lh * 8]);
      acc = __builtin_amdgcn_mfma_f32_16x16x32_bf16(af, bf, acc, 0, 0, 0);
    }
    __syncthreads();
  }
#pragma unroll
  for (int j = 0; j < 4; ++j)
    Ul[lh * 4 + j][w * 16 + l16] = acc[j];
  __syncthreads();
  if (w == 0) {
    int g = blockIdx.x;
    float as = aSig[lane];
    float h = 0.0f;
#pragma unroll
    for (int i = 0; i < 16; ++i) {
      h = fmaf(as, h, Ul[i][lane]);
      Uloc[(size_t)(g * 16 + i) * 64 + lane] = h;
    }
    carry[(size_t)g * 64 + lane] = h;
  }
}

// ---------------- scan fix v2 (R18-proven): batched prefix + apply + write Z ------
__global__ __launch_bounds__(128) void scan_fix2(const float* __restrict__ aSig,
    const float* __restrict__ Uloc, const float* __restrict__ carry,
    ushort* __restrict__ Z) {
  int w = threadIdx.x >> 6, s = threadIdx.x & 63;
  int g = blockIdx.x * 2 + w;          // 0..1023
  int b = g >> 8, c = g & 255;
  float as = aSig[s];
  float aL = as;
#pragma unroll
  for (int q = 0; q < 4; ++q) aL *= aL;  // as^16
  const float* cb = carry + ((size_t)b << 8) * 64 + s;
  float H = 0.0f;
  for (int c0 = 0; c0 < 256; c0 += 16) {
    if (c0 >= c) break;                  // wave-uniform
    float v[16];
#pragma unroll
    for (int i = 0; i < 16; ++i) v[i] = cb[(size_t)(c0 + i) * 64];
#pragma unroll
    for (int i = 0; i < 16; ++i)
      if (c0 + i < c) H = fmaf(aL, H, v[i]);   // wave-uniform predicate
  }
  float p = as;
  size_t ubase = (size_t)g * 16 * 64 + s;
  size_t zbase = (size_t)(g * 16) * KBIG + s;
#pragma unroll
  for (int i = 0; i < 16; ++i) {
    float h = fmaf(p, H, Uloc[ubase + (size_t)i * 64]);
    p *= as;
    Z[zbase + (size_t)i * KBIG] = f2b(h);
  }
}

// ---------------- 128x128 GEMM (R17-proven BEST, LOCKED): BK=64, 2 blocks/CU ----------
// 4 waves (2x2), 64x64 wave-tile, 64KB LDS dbuf, conflict-free XOR swizzle,
// stage t+2 two-ahead, counted vmcnt(8). 43.0 us ≈ 850 TF — measured ceiling of
// the lockstep-schedule family (9 structural variants bracketed 43-60 us, incl.
// a faithful 8-phase template port at 52 us).
__global__ __launch_bounds__(256, 2) void gemm128(const ushort* __restrict__ A, int lda,
                                                  const ushort* __restrict__ Bt, int ldb,
                                                  float* __restrict__ Cc, int ldc, int K) {
  extern __shared__ __align__(128) char smem[];  // buf{0,1} x (A 16K + B 16K) = 64 KB
  const int tid = threadIdx.x;
  const int wid = tid >> 6, lane = tid & 63;
  const int wm = wid >> 1, wn = wid & 1;          // 2 x 2 wave grid
  const int l16 = lane & 15, lh = lane >> 4;

  int bid = blockIdx.x;
  int swz = (bid & 7) * ((int)gridDim.x >> 3) + (bid >> 3);  // 1024 % 8 == 0
  const int bmRow = (swz >> 3) * 128;
  const int bnCol = (swz & 7) * 128;
  const int NT = K / 64;                // 17

  const int cswz = ((lh ^ (l16 & 7)) << 4);
  const int sRow = lane >> 3;
  const int sCol = (((lane & 7) ^ (lane >> 3)) << 3);

  const ushort* aBase = A + (size_t)(bmRow + wid * 8 + sRow) * lda + sCol;
  const ushort* bBase = Bt + (size_t)(bnCol + wid * 8 + sRow) * ldb + sCol;

  f32x4 acc[4][4] = {};
  bf16x8 aR[8], bR[8];

  auto stageA = [&](int buf, int t) {
    const ushort* g = aBase + (size_t)t * 64;
    char* d = smem + buf * 32768 + (wid * 8) * 128;
#pragma unroll
    for (int h = 0; h < 4; ++h)
      gld_lds16(g + (size_t)(h * 32) * lda, d + h * 32 * 128);
  };
  auto stageB = [&](int buf, int t) {
    const ushort* g = bBase + (size_t)t * 64;
    char* d = smem + buf * 32768 + 16384 + (wid * 8) * 128;
#pragma unroll
    for (int h = 0; h < 4; ++h)
      gld_lds16(g + (size_t)(h * 32) * ldb, d + h * 32 * 128);
  };
  auto readA = [&](int buf) {
#pragma unroll
    for (int m = 0; m < 4; ++m)
#pragma unroll
      for (int ks = 0; ks < 2; ++ks)
        aR[m * 2 + ks] = *reinterpret_cast<const bf16x8*>(
            smem + buf * 32768 + (wm * 64 + m * 16 + l16) * 128 + (cswz ^ (ks * 64)));
  };
  auto readB = [&](int buf) {
#pragma unroll
    for (int n = 0; n < 4; ++n)
#pragma unroll
      for (int ks = 0; ks < 2; ++ks)
        bR[n * 2 + ks] = *reinterpret_cast<const bf16x8*>(
            smem + buf * 32768 + 16384 + (wn * 64 + n * 16 + l16) * 128 + (cswz ^ (ks * 64)));
  };

  stageA(0, 0); stageB(0, 0);
  stageA(1, 1); stageB(1, 1);
  VMCNT8();
  BARRIER();

  for (int t = 0; t < NT; ++t) {
    const int buf = t & 1;
    const bool st2 = (t + 2 < NT);
    readA(buf); readB(buf);
    BARRIER();                     // all reads of buf issued block-wide
    if (st2) { stageA(buf, t + 2); stageB(buf, t + 2); }
    __builtin_amdgcn_s_setprio(1);
#pragma unroll
    for (int ks = 0; ks < 2; ++ks)
#pragma unroll
      for (int m = 0; m < 4; ++m)
#pragma unroll
        for (int n = 0; n < 4; ++n)
          acc[m][n] = __builtin_amdgcn_mfma_f32_16x16x32_bf16(
              aR[m * 2 + ks], bR[n * 2 + ks], acc[m][n], 0, 0, 0);
    __builtin_amdgcn_s_setprio(0);
    if (st2) { VMCNT8(); } else { VMCNT0(); }   // drain t+1's stages; t+2's in flight
    BARRIER();                     // publish buf^1 (tile t+1)
  }

  // epilogue: C/D 16x16 layout: col = l16, row = lh*4 + j
#pragma unroll
  for (int m = 0; m < 4; ++m)
#pragma unroll
    for (int n = 0; n < 4; ++n)
#pragma unroll
      for (int j = 0; j < 4; ++j) {
        int r = bmRow + wm * 64 + m * 16 + lh * 4 + j;
        int c = bnCol + wn * 64 + n * 16 + l16;
        Cc[(size_t)r * ldc + c] = acc[m][n][j];
      }
}

extern "C" void kernel_launch(void* const* d_in, const int* in_sizes, int n_in,
                              void* d_out, int out_size, void* d_ws, size_t ws_size,
                              hipStream_t stream) {
  const float* x      = (const float*)d_in[0];
  const float* A_diag = (const float*)d_in[1];
  const float* B      = (const float*)d_in[2];
  const float* C      = (const float*)d_in[3];
  const float* D      = (const float*)d_in[4];
  float* y = (float*)d_out;

  char* w = (char*)d_ws;
  ushort* Z     = (ushort*)(w);                 // [16384][1088] bf16  35,651,584
  ushort* Wt    = (ushort*)(w + 35651584);      // [1024][1088] bf16    2,228,224
  ushort* Btu   = (ushort*)(w + 37879808);      // [64][1024] bf16        131,072
  float*  Uloc  = (float*) (w + 38010880);      // [16384][64] f32      4,194,304
  float*  carry = (float*) (w + 42205184);      // [1024][64] f32         262,144
  float*  aSig  = (float*) (w + 42467328);      // [64] f32

  (void)hipFuncSetAttribute(reinterpret_cast<const void*>(&gemm128),
                            hipFuncAttributeMaxDynamicSharedMemorySize, 65536);

  prep_wb<<<dim3(288), dim3(256), 0, stream>>>(A_diag, B, C, D, Wt, Btu, aSig);
  fused_xu<<<dim3(1024), dim3(256), 0, stream>>>(x, Btu, aSig, Z, Uloc, carry);
  scan_fix2<<<dim3(512), dim3(128), 0, stream>>>(aSig, Uloc, carry, Z);
  // y = [h|x] @ [C;D] : M=16384, N=1024, K=1088  (128x128 tiles -> 1024 blocks, 2/CU)
  gemm128<<<dim3(128 * 8), dim3(256), 65536, stream>>>(Z, KBIG, Wt, KBIG, y, DMODEL, KBIG);
}